// Round 8
// baseline (390.030 us; speedup 1.0000x reference)
//
#include <hip/hip_runtime.h>
#include <cstdint>

#define CCH 512
#define HW  4096
#define WDIM 64
#define NBATCH 8
#define CHW ((size_t)CCH * HW)

typedef __attribute__((ext_vector_type(8))) short bf16x8;
typedef __attribute__((ext_vector_type(4))) float f32x4;
typedef __attribute__((ext_vector_type(4))) unsigned u32x4;

__device__ __forceinline__ unsigned short f2bf(float x) {
  unsigned u = __float_as_uint(x);
  unsigned r = (u + 0x7FFFu + ((u >> 16) & 1u)) >> 16;
  return (unsigned short)r;
}
__device__ __forceinline__ float bf2f(unsigned short h) {
  return __uint_as_float(((unsigned)h) << 16);
}

__device__ __forceinline__ void gl_lds16(const void* g, void* l) {
  __builtin_amdgcn_global_load_lds(
      (const __attribute__((address_space(1))) void*)g,
      (__attribute__((address_space(3))) void*)l, 16, 0, 0);
}

// ---------------------------------------------------------------------------
// P0: split W (fp32 [o][c]) -> bf16 hi/lo (RNE). Whl: [br][hi|lo] ushort.
// ---------------------------------------------------------------------------
__global__ __launch_bounds__(256) void wsplit_k(
    const float* __restrict__ Wo, const float* __restrict__ Wsr,
    unsigned short* __restrict__ Whl) {
  const int br = blockIdx.y;
  const float* W = br ? Wsr : Wo;
  const int i = blockIdx.x * 256 + threadIdx.x;
  const float x = W[i];
  const unsigned short h = f2bf(x);
  unsigned short* dst = Whl + (size_t)br * 524288;
  dst[i] = h;
  dst[262144 + i] = f2bf(x - bf2f(h));
}

// ---------------------------------------------------------------------------
// K1 = v7 EXACT (measured best: 69-72 us/dispatch, 0 bank conflicts,
// 4 blocks/CU). Ledger of failed perturbations pinning this structure:
//  * v6 (64KB dbuf, 1 barrier): 106 us — occupancy 4->2 blocks/CU.
//  * v8 (A direct from global): 127 us — L2 latency on MFMA path.
//  * v9 (setprio): 79.5 us — de-synced co-resident blocks, FETCH +42%.
//  * v10 (A-dbuf @ 3 blocks/CU): 90.9 us — dur scaled with lost occupancy.
// ---------------------------------------------------------------------------
__global__ __launch_bounds__(256, 4) void mfma_conv_k(
    const unsigned short* __restrict__ Whl,
    const float* __restrict__ opt, const float* __restrict__ sar,
    float* __restrict__ F, int b0) {
  const int z = blockIdx.z;
  const int br = z & 1, bl = z >> 1;
  const unsigned short* Ah_g = Whl + (size_t)br * 524288;
  const unsigned short* Al_g = Ah_g + 262144;
  const float* Xb = (br ? sar : opt) + (size_t)(b0 + bl) * CHW;
  const int n0 = blockIdx.x * 128, m0 = blockIdx.y * 128;

  __shared__ __align__(16) unsigned short Ahs[128 * 32];  // 8 KB
  __shared__ __align__(16) unsigned short Als[128 * 32];  // 8 KB
  __shared__ __align__(16) unsigned short Xhs[128 * 32];  // 8 KB
  __shared__ __align__(16) unsigned short Xls[128 * 32];  // 8 KB

  const int tid = threadIdx.x;
  const int wave = tid >> 6, lane = tid & 63;
  const int wm = (wave >> 1) * 64, wn = (wave & 1) * 64;

  f32x4 acc[4][4] = {};

  const int rl = lane >> 2;
  const int kcA = (((lane & 3) ^ ((lane >> 3) & 3)) * 8);

  const int rX = lane;
  const int pX = (wave ^ ((lane >> 1) & 3)) * 8;

  const int fr = lane & 15;
  const int kq = (((lane >> 4) ^ ((lane >> 1) & 3)) * 8);

  float xv[16];

  auto stageA = [&](int k0) {
#pragma unroll
    for (int q = 0; q < 2; ++q) {
      const int rbase = wave * 32 + q * 16;
      const int r = rbase + rl;
      gl_lds16(Ah_g + (size_t)(m0 + r) * CCH + k0 + kcA, &Ahs[rbase * 32]);
      gl_lds16(Al_g + (size_t)(m0 + r) * CCH + k0 + kcA, &Als[rbase * 32]);
    }
  };

  auto loadX = [&](int k0) {
#pragma unroll
    for (int s = 0; s < 8; ++s) {
      const size_t rowb = (size_t)(k0 + wave * 8 + s) * HW + n0;
      xv[s] = Xb[rowb + rX];
      xv[8 + s] = Xb[rowb + 64 + rX];
    }
  };

  auto writeX = [&]() {
    u32x4 h0, h1, l0, l1;
#pragma unroll
    for (int w = 0; w < 4; ++w) {
      const unsigned a0 = __float_as_uint(xv[2 * w]);
      const unsigned a1 = __float_as_uint(xv[2 * w + 1]);
      const unsigned b0_ = __float_as_uint(xv[8 + 2 * w]);
      const unsigned b1_ = __float_as_uint(xv[8 + 2 * w + 1]);
      h0[w] = __builtin_amdgcn_perm(a1, a0, 0x07060302u);
      h1[w] = __builtin_amdgcn_perm(b1_, b0_, 0x07060302u);
      const float la0 = xv[2 * w] - __uint_as_float(a0 & 0xFFFF0000u);
      const float la1 = xv[2 * w + 1] - __uint_as_float(a1 & 0xFFFF0000u);
      const float lb0 = xv[8 + 2 * w] - __uint_as_float(b0_ & 0xFFFF0000u);
      const float lb1 = xv[8 + 2 * w + 1] - __uint_as_float(b1_ & 0xFFFF0000u);
      l0[w] = __builtin_amdgcn_perm(__float_as_uint(la1), __float_as_uint(la0),
                                    0x07060302u);
      l1[w] = __builtin_amdgcn_perm(__float_as_uint(lb1), __float_as_uint(lb0),
                                    0x07060302u);
    }
    *(u32x4*)&Xhs[rX * 32 + pX] = h0;
    *(u32x4*)&Xhs[(rX + 64) * 32 + pX] = h1;
    *(u32x4*)&Xls[rX * 32 + pX] = l0;
    *(u32x4*)&Xls[(rX + 64) * 32 + pX] = l1;
  };

  auto compute = [&]() {
    bf16x8 bh[4], blo[4];
#pragma unroll
    for (int j = 0; j < 4; ++j) {
      const int n = wn + j * 16 + fr;
      bh[j] = *(const bf16x8*)&Xhs[n * 32 + kq];
      blo[j] = *(const bf16x8*)&Xls[n * 32 + kq];
    }
#pragma unroll
    for (int i = 0; i < 4; ++i) {
      const int m = wm + i * 16 + fr;
      const bf16x8 ah = *(const bf16x8*)&Ahs[m * 32 + kq];
      const bf16x8 al = *(const bf16x8*)&Als[m * 32 + kq];
#pragma unroll
      for (int j = 0; j < 4; ++j) {
        acc[i][j] = __builtin_amdgcn_mfma_f32_16x16x32_bf16(ah, bh[j], acc[i][j], 0, 0, 0);
        acc[i][j] = __builtin_amdgcn_mfma_f32_16x16x32_bf16(ah, blo[j], acc[i][j], 0, 0, 0);
        acc[i][j] = __builtin_amdgcn_mfma_f32_16x16x32_bf16(al, bh[j], acc[i][j], 0, 0, 0);
      }
    }
  };

  // prologue: stage tile 0
  stageA(0);
  loadX(0);
  writeX();
  __syncthreads();

  for (int t = 0; t < 16; ++t) {
    if (t < 15) loadX((t + 1) * 32);  // issue early: latency elapses under compute
    compute();
    __syncthreads();                  // all waves done reading A/X LDS
    if (t < 15) {
      stageA((t + 1) * 32);           // gl_lds overwrite (L2-hot W data)
      writeX();                       // convert + conflict-free ds_write
      __syncthreads();                // staged tile visible
    }
  }

  float* Fb = F + (size_t)z * CHW;
  const int col = lane & 15, rq = (lane >> 4) * 4;
#pragma unroll
  for (int i = 0; i < 4; ++i)
#pragma unroll
    for (int j = 0; j < 4; ++j) {
      const int n = n0 + wn + j * 16 + col;
#pragma unroll
      for (int r = 0; r < 4; ++r) {
        const int m = m0 + wm + i * 16 + rq + r;
        Fb[(size_t)m * HW + n] = acc[i][j][r];
      }
    }
}

// ---------------------------------------------------------------------------
// K2 v3 (R3-exact): S = F^T F per (z,c) via split-bf16 MFMA. v4's
// drop-Fs-staging variant measured NEUTRAL (R7 remaining 201.5 vs 201.6) —
// reverted to keep this round's diff isolated to softmax.
// ---------------------------------------------------------------------------
#define FT_S 72
__global__ __launch_bounds__(256, 4) void gram_k(
    const float* __restrict__ F, float* __restrict__ S) {
  const size_t base = ((size_t)blockIdx.y * CCH + blockIdx.x) * HW;
  const float* Fc = F + base;
  float* Sc = S + base;

  __shared__ float Fs[64 * 64];                // 16 KB, unpadded
  __shared__ unsigned short FtH[64 * FT_S];
  __shared__ unsigned short FtL[64 * FT_S];

  const int tid = threadIdx.x;
  const int wave = tid >> 6, lane = tid & 63;

#pragma unroll
  for (int t = 0; t < 4; ++t) {
    const int off = (wave * 4 + t) * 256;
    gl_lds16(Fc + off + lane * 4, &Fs[off]);
  }
  __syncthreads();

  {
    const int w = lane;
    const int hc = wave * 16;
    unsigned short hb[16], lb[16];
#pragma unroll
    for (int k = 0; k < 16; ++k) {
      const float x = Fs[(hc + k) * 64 + w];
      const unsigned short h = f2bf(x);
      hb[k] = h;
      lb[k] = f2bf(x - bf2f(h));
    }
    unsigned short* dh = &FtH[w * FT_S + hc];
    unsigned short* dl = &FtL[w * FT_S + hc];
    *(uint4*)(dh + 0) = *(uint4*)&hb[0];
    *(uint4*)(dh + 8) = *(uint4*)&hb[8];
    *(uint4*)(dl + 0) = *(uint4*)&lb[0];
    *(uint4*)(dl + 8) = *(uint4*)&lb[8];
  }
  __syncthreads();

  const int wm = (wave >> 1) * 32, wn = (wave & 1) * 32;
  const int fr = lane & 15, kq = (lane >> 4) * 8;

  f32x4 acc[2][2] = {};
#pragma unroll
  for (int kcc = 0; kcc < 2; ++kcc) {
    bf16x8 ah[2], al[2], bh[2], bl[2];
#pragma unroll
    for (int i = 0; i < 2; ++i) {
      ah[i] = *(const bf16x8*)&FtH[(wm + i * 16 + fr) * FT_S + kcc * 32 + kq];
      al[i] = *(const bf16x8*)&FtL[(wm + i * 16 + fr) * FT_S + kcc * 32 + kq];
      bh[i] = *(const bf16x8*)&FtH[(wn + i * 16 + fr) * FT_S + kcc * 32 + kq];
      bl[i] = *(const bf16x8*)&FtL[(wn + i * 16 + fr) * FT_S + kcc * 32 + kq];
    }
#pragma unroll
    for (int i = 0; i < 2; ++i)
#pragma unroll
      for (int j = 0; j < 2; ++j) {
        acc[i][j] = __builtin_amdgcn_mfma_f32_16x16x32_bf16(ah[i], bh[j], acc[i][j], 0, 0, 0);
        acc[i][j] = __builtin_amdgcn_mfma_f32_16x16x32_bf16(ah[i], bl[j], acc[i][j], 0, 0, 0);
        acc[i][j] = __builtin_amdgcn_mfma_f32_16x16x32_bf16(al[i], bh[j], acc[i][j], 0, 0, 0);
      }
  }

  const int rq = (lane >> 4) * 4;
#pragma unroll
  for (int i = 0; i < 2; ++i)
#pragma unroll
    for (int j = 0; j < 2; ++j) {
      const int n = wn + j * 16 + fr;
#pragma unroll
      for (int r = 0; r < 4; ++r) {
        const int m = wm + i * 16 + rq + r;
        Sc[m * 64 + n] = acc[i][j][r];
      }
    }
}

// ---------------------------------------------------------------------------
// K3 v6: softmax over c + hadamard + output. j-QUARTER split:
// grid (64, 4, nb) = 1024 blocks of 256 threads, 16.6 KB LDS -> 4+
// blocks/CU resident (was 512 blocks of 512 thr @ 33 KB = 2 blocks/CU with
// a serial middle phase idling 7/8 of the block). Same traffic; 2x TLP for
// latency hiding. S/F are freshly-written and L3-resident, so the finer
// 64 B read granularity is absorbed by L3.
// ---------------------------------------------------------------------------
__global__ __launch_bounds__(256, 6) void softmax_fuse_k(
    const float* __restrict__ S, const float* __restrict__ Fbuf,
    float* __restrict__ Out) {
  const int i = blockIdx.x;   // 0..63
  const int jq = blockIdx.y;  // 0..3 (j-quarter)
  const int b = blockIdx.z;
  const int tid = threadIdx.x;
  const int jl = (tid & 3) * 4;  // 0..12 within the quarter
  const int g = tid >> 2;        // 0..63 (8 c's each)

  const size_t rowO = (size_t)(b * 2) * CHW + (size_t)i * WDIM + jq * 16;
  const size_t rowS = rowO + CHW;

  float4 xoc[8], xsc[8];
  float mo[4], lo[4], ms[4], ls[4];
#pragma unroll
  for (int k = 0; k < 4; ++k) { mo[k] = -1e30f; ms[k] = -1e30f; lo[k] = 0.f; ls[k] = 0.f; }

#pragma unroll
  for (int cc = 0; cc < 8; ++cc) {
    const int c = g * 8 + cc;
    const size_t off = (size_t)c * HW + jl;
    xoc[cc] = *(const float4*)&S[rowO + off];
    xsc[cc] = *(const float4*)&S[rowS + off];
    mo[0] = fmaxf(mo[0], xoc[cc].x); mo[1] = fmaxf(mo[1], xoc[cc].y);
    mo[2] = fmaxf(mo[2], xoc[cc].z); mo[3] = fmaxf(mo[3], xoc[cc].w);
    ms[0] = fmaxf(ms[0], xsc[cc].x); ms[1] = fmaxf(ms[1], xsc[cc].y);
    ms[2] = fmaxf(ms[2], xsc[cc].z); ms[3] = fmaxf(ms[3], xsc[cc].w);
  }
#pragma unroll
  for (int cc = 0; cc < 8; ++cc) {
    lo[0] += __expf(xoc[cc].x - mo[0]); lo[1] += __expf(xoc[cc].y - mo[1]);
    lo[2] += __expf(xoc[cc].z - mo[2]); lo[3] += __expf(xoc[cc].w - mo[3]);
    ls[0] += __expf(xsc[cc].x - ms[0]); ls[1] += __expf(xsc[cc].y - ms[1]);
    ls[2] += __expf(xsc[cc].z - ms[2]); ls[3] += __expf(xsc[cc].w - ms[3]);
  }

  __shared__ float sm[2][64][16];
  __shared__ float sl[2][64][16];
  __shared__ float Mf[2][16];
  __shared__ float Li[2][16];

  *(float4*)&sm[0][g][jl] = make_float4(mo[0], mo[1], mo[2], mo[3]);
  *(float4*)&sl[0][g][jl] = make_float4(lo[0], lo[1], lo[2], lo[3]);
  *(float4*)&sm[1][g][jl] = make_float4(ms[0], ms[1], ms[2], ms[3]);
  *(float4*)&sl[1][g][jl] = make_float4(ls[0], ls[1], ls[2], ls[3]);
  __syncthreads();

  if (tid < 32) {
    const int brx = tid >> 4, j = tid & 15;
    float M = -1e30f;
#pragma unroll 16
    for (int t = 0; t < 64; ++t) M = fmaxf(M, sm[brx][t][j]);
    float L = 0.f;
#pragma unroll 16
    for (int t = 0; t < 64; ++t) L += sl[brx][t][j] * __expf(sm[brx][t][j] - M);
    Mf[brx][j] = M;
    Li[brx][j] = 1.f / L;
  }
  __syncthreads();

  float4 Mo4 = *(const float4*)&Mf[0][jl];
  float4 iLo4 = *(const float4*)&Li[0][jl];
  float4 Ms4 = *(const float4*)&Mf[1][jl];
  float4 iLs4 = *(const float4*)&Li[1][jl];
  float Mov[4] = {Mo4.x, Mo4.y, Mo4.z, Mo4.w};
  float iLov[4] = {iLo4.x, iLo4.y, iLo4.z, iLo4.w};
  float Msv[4] = {Ms4.x, Ms4.y, Ms4.z, Ms4.w};
  float iLsv[4] = {iLs4.x, iLs4.y, iLs4.z, iLs4.w};

#pragma unroll
  for (int cc = 0; cc < 8; ++cc) {
    const int c = g * 8 + cc;
    const size_t off = (size_t)c * HW + jl;
    float4 fo = *(const float4*)&Fbuf[rowO + off];
    float4 fs = *(const float4*)&Fbuf[rowS + off];
    float xov[4] = {xoc[cc].x, xoc[cc].y, xoc[cc].z, xoc[cc].w};
    float xsv[4] = {xsc[cc].x, xsc[cc].y, xsc[cc].z, xsc[cc].w};
    float fov[4] = {fo.x, fo.y, fo.z, fo.w};
    float fsv[4] = {fs.x, fs.y, fs.z, fs.w};
    float ov[4];
#pragma unroll
    for (int k = 0; k < 4; ++k) {
      const float ho = __expf(xov[k] - Mov[k]) * iLov[k];
      const float hs = __expf(xsv[k] - Msv[k]) * iLsv[k];
      float h2 = ho * hs;
      h2 *= h2;
      ov[k] = fov[k] * fsv[k] * h2;
    }
    *(float4*)&Out[(size_t)b * CHW + (size_t)c * HW + (size_t)i * WDIM +
                   jq * 16 + jl] = make_float4(ov[0], ov[1], ov[2], ov[3]);
  }
}

// ---------------------------------------------------------------------------
extern "C" void kernel_launch(void* const* d_in, const int* in_sizes, int n_in,
                              void* d_out, int out_size, void* d_ws, size_t ws_size,
                              hipStream_t stream) {
  const float* opt = (const float*)d_in[0];
  const float* sar = (const float*)d_in[1];
  const float* Wo  = (const float*)d_in[2];
  const float* Wsr = (const float*)d_in[3];
  float* out = (float*)d_out;

  // workspace: Whl | F | S
  unsigned short* Whl = (unsigned short*)d_ws;
  const size_t whlElems = 2u * 2u * 262144u;     // 2 MB
  const size_t perBl = 2 * CHW;                  // elems per batch (both br)
  const size_t perBlBytes = perBl * 8;           // F(4) + S(4)
  int bc = (int)((ws_size - whlElems * 2) / perBlBytes);
  if (bc < 1) bc = 1;
  if (bc > NBATCH) bc = NBATCH;
  const int passes = (NBATCH + bc - 1) / bc;
  const int nbp = (NBATCH + passes - 1) / passes;

  float* Fbuf = (float*)(Whl + whlElems);
  float* Sbuf = Fbuf + (size_t)bc * perBl;

  hipLaunchKernelGGL(wsplit_k, dim3(1024, 2), dim3(256), 0, stream, Wo, Wsr, Whl);

  for (int b0 = 0; b0 < NBATCH; b0 += nbp) {
    const int nb = (NBATCH - b0 < nbp) ? (NBATCH - b0) : nbp;

    hipLaunchKernelGGL(mfma_conv_k, dim3(32, 4, nb * 2), dim3(256), 0, stream,
                       Whl, opt, sar, Fbuf, b0);

    hipLaunchKernelGGL(gram_k, dim3(CCH, nb * 2), dim3(256), 0, stream,
                       Fbuf, Sbuf);

    hipLaunchKernelGGL(softmax_fuse_k, dim3(WDIM, 4, nb), dim3(256), 0, stream,
                       Sbuf, Fbuf, out + (size_t)b0 * CHW);
  }
}

// Round 9
// 337.961 us; speedup vs baseline: 1.1541x; 1.1541x over previous
//
#include <hip/hip_runtime.h>
#include <cstdint>

#define CCH 512
#define HW  4096
#define WDIM 64
#define NBATCH 8
#define CHW ((size_t)CCH * HW)

typedef __attribute__((ext_vector_type(8))) short bf16x8;
typedef __attribute__((ext_vector_type(4))) float f32x4;
typedef __attribute__((ext_vector_type(4))) unsigned u32x4;

__device__ __forceinline__ unsigned short f2bf(float x) {
  unsigned u = __float_as_uint(x);
  unsigned r = (u + 0x7FFFu + ((u >> 16) & 1u)) >> 16;
  return (unsigned short)r;
}
__device__ __forceinline__ float bf2f(unsigned short h) {
  return __uint_as_float(((unsigned)h) << 16);
}

__device__ __forceinline__ void gl_lds16(const void* g, void* l) {
  __builtin_amdgcn_global_load_lds(
      (const __attribute__((address_space(1))) void*)g,
      (__attribute__((address_space(3))) void*)l, 16, 0, 0);
}

// ---------------------------------------------------------------------------
// P0: split W (fp32 [o][c]) -> bf16 hi/lo (RNE). Whl: [br][hi|lo] ushort.
// ---------------------------------------------------------------------------
__global__ __launch_bounds__(256) void wsplit_k(
    const float* __restrict__ Wo, const float* __restrict__ Wsr,
    unsigned short* __restrict__ Whl) {
  const int br = blockIdx.y;
  const float* W = br ? Wsr : Wo;
  const int i = blockIdx.x * 256 + threadIdx.x;
  const float x = W[i];
  const unsigned short h = f2bf(x);
  unsigned short* dst = Whl + (size_t)br * 524288;
  dst[i] = h;
  dst[262144 + i] = f2bf(x - bf2f(h));
}

// ---------------------------------------------------------------------------
// K1 = v7 EXACT (measured best: 69.0 us/dispatch @ R3, 0 bank conflicts,
// 4 blocks/CU). Ledger of failed perturbations pinning this structure:
//  * v6 (64KB dbuf, 1 barrier): 106 us — occupancy 4->2 blocks/CU.
//  * v8 (A direct from global): 127 us — L2 latency on MFMA path; L2 read
//    storm broke F write-combining (WRITE 66->143 MB).
//  * v9 (setprio): 79.5 us — de-synced co-resident blocks, FETCH +42%.
//  * v10 (A-dbuf @ 3 blocks/CU): 90.9 us — dur scaled with lost occupancy;
//    compiler's vmcnt(0)-at-barrier nullifies source-level prefetch.
// Conclusion: 2-barrier + 32 KB + 4 blocks/CU is this structure's optimum.
// ---------------------------------------------------------------------------
__global__ __launch_bounds__(256, 4) void mfma_conv_k(
    const unsigned short* __restrict__ Whl,
    const float* __restrict__ opt, const float* __restrict__ sar,
    float* __restrict__ F, int b0) {
  const int z = blockIdx.z;
  const int br = z & 1, bl = z >> 1;
  const unsigned short* Ah_g = Whl + (size_t)br * 524288;
  const unsigned short* Al_g = Ah_g + 262144;
  const float* Xb = (br ? sar : opt) + (size_t)(b0 + bl) * CHW;
  const int n0 = blockIdx.x * 128, m0 = blockIdx.y * 128;

  __shared__ __align__(16) unsigned short Ahs[128 * 32];  // 8 KB
  __shared__ __align__(16) unsigned short Als[128 * 32];  // 8 KB
  __shared__ __align__(16) unsigned short Xhs[128 * 32];  // 8 KB
  __shared__ __align__(16) unsigned short Xls[128 * 32];  // 8 KB

  const int tid = threadIdx.x;
  const int wave = tid >> 6, lane = tid & 63;
  const int wm = (wave >> 1) * 64, wn = (wave & 1) * 64;

  f32x4 acc[4][4] = {};

  const int rl = lane >> 2;
  const int kcA = (((lane & 3) ^ ((lane >> 3) & 3)) * 8);

  const int rX = lane;
  const int pX = (wave ^ ((lane >> 1) & 3)) * 8;

  const int fr = lane & 15;
  const int kq = (((lane >> 4) ^ ((lane >> 1) & 3)) * 8);

  float xv[16];

  auto stageA = [&](int k0) {
#pragma unroll
    for (int q = 0; q < 2; ++q) {
      const int rbase = wave * 32 + q * 16;
      const int r = rbase + rl;
      gl_lds16(Ah_g + (size_t)(m0 + r) * CCH + k0 + kcA, &Ahs[rbase * 32]);
      gl_lds16(Al_g + (size_t)(m0 + r) * CCH + k0 + kcA, &Als[rbase * 32]);
    }
  };

  auto loadX = [&](int k0) {
#pragma unroll
    for (int s = 0; s < 8; ++s) {
      const size_t rowb = (size_t)(k0 + wave * 8 + s) * HW + n0;
      xv[s] = Xb[rowb + rX];
      xv[8 + s] = Xb[rowb + 64 + rX];
    }
  };

  auto writeX = [&]() {
    u32x4 h0, h1, l0, l1;
#pragma unroll
    for (int w = 0; w < 4; ++w) {
      const unsigned a0 = __float_as_uint(xv[2 * w]);
      const unsigned a1 = __float_as_uint(xv[2 * w + 1]);
      const unsigned b0_ = __float_as_uint(xv[8 + 2 * w]);
      const unsigned b1_ = __float_as_uint(xv[8 + 2 * w + 1]);
      h0[w] = __builtin_amdgcn_perm(a1, a0, 0x07060302u);
      h1[w] = __builtin_amdgcn_perm(b1_, b0_, 0x07060302u);
      const float la0 = xv[2 * w] - __uint_as_float(a0 & 0xFFFF0000u);
      const float la1 = xv[2 * w + 1] - __uint_as_float(a1 & 0xFFFF0000u);
      const float lb0 = xv[8 + 2 * w] - __uint_as_float(b0_ & 0xFFFF0000u);
      const float lb1 = xv[8 + 2 * w + 1] - __uint_as_float(b1_ & 0xFFFF0000u);
      l0[w] = __builtin_amdgcn_perm(__float_as_uint(la1), __float_as_uint(la0),
                                    0x07060302u);
      l1[w] = __builtin_amdgcn_perm(__float_as_uint(lb1), __float_as_uint(lb0),
                                    0x07060302u);
    }
    *(u32x4*)&Xhs[rX * 32 + pX] = h0;
    *(u32x4*)&Xhs[(rX + 64) * 32 + pX] = h1;
    *(u32x4*)&Xls[rX * 32 + pX] = l0;
    *(u32x4*)&Xls[(rX + 64) * 32 + pX] = l1;
  };

  auto compute = [&]() {
    bf16x8 bh[4], blo[4];
#pragma unroll
    for (int j = 0; j < 4; ++j) {
      const int n = wn + j * 16 + fr;
      bh[j] = *(const bf16x8*)&Xhs[n * 32 + kq];
      blo[j] = *(const bf16x8*)&Xls[n * 32 + kq];
    }
#pragma unroll
    for (int i = 0; i < 4; ++i) {
      const int m = wm + i * 16 + fr;
      const bf16x8 ah = *(const bf16x8*)&Ahs[m * 32 + kq];
      const bf16x8 al = *(const bf16x8*)&Als[m * 32 + kq];
#pragma unroll
      for (int j = 0; j < 4; ++j) {
        acc[i][j] = __builtin_amdgcn_mfma_f32_16x16x32_bf16(ah, bh[j], acc[i][j], 0, 0, 0);
        acc[i][j] = __builtin_amdgcn_mfma_f32_16x16x32_bf16(ah, blo[j], acc[i][j], 0, 0, 0);
        acc[i][j] = __builtin_amdgcn_mfma_f32_16x16x32_bf16(al, bh[j], acc[i][j], 0, 0, 0);
      }
    }
  };

  // prologue: stage tile 0
  stageA(0);
  loadX(0);
  writeX();
  __syncthreads();

  for (int t = 0; t < 16; ++t) {
    if (t < 15) loadX((t + 1) * 32);  // issue early: latency elapses under compute
    compute();
    __syncthreads();                  // all waves done reading A/X LDS
    if (t < 15) {
      stageA((t + 1) * 32);           // gl_lds overwrite (L2-hot W data)
      writeX();                       // convert + conflict-free ds_write
      __syncthreads();                // staged tile visible
    }
  }

  float* Fb = F + (size_t)z * CHW;
  const int col = lane & 15, rq = (lane >> 4) * 4;
#pragma unroll
  for (int i = 0; i < 4; ++i)
#pragma unroll
    for (int j = 0; j < 4; ++j) {
      const int n = n0 + wn + j * 16 + col;
#pragma unroll
      for (int r = 0; r < 4; ++r) {
        const int m = m0 + wm + i * 16 + rq + r;
        Fb[(size_t)m * HW + n] = acc[i][j][r];
      }
    }
}

// ---------------------------------------------------------------------------
// K2 v3 (R3-exact): S = F^T F per (z,c) via split-bf16 MFMA.
// ---------------------------------------------------------------------------
#define FT_S 72
__global__ __launch_bounds__(256, 4) void gram_k(
    const float* __restrict__ F, float* __restrict__ S) {
  const size_t base = ((size_t)blockIdx.y * CCH + blockIdx.x) * HW;
  const float* Fc = F + base;
  float* Sc = S + base;

  __shared__ float Fs[64 * 64];                // 16 KB, unpadded
  __shared__ unsigned short FtH[64 * FT_S];
  __shared__ unsigned short FtL[64 * FT_S];

  const int tid = threadIdx.x;
  const int wave = tid >> 6, lane = tid & 63;

#pragma unroll
  for (int t = 0; t < 4; ++t) {
    const int off = (wave * 4 + t) * 256;
    gl_lds16(Fc + off + lane * 4, &Fs[off]);
  }
  __syncthreads();

  {
    const int w = lane;
    const int hc = wave * 16;
    unsigned short hb[16], lb[16];
#pragma unroll
    for (int k = 0; k < 16; ++k) {
      const float x = Fs[(hc + k) * 64 + w];
      const unsigned short h = f2bf(x);
      hb[k] = h;
      lb[k] = f2bf(x - bf2f(h));
    }
    unsigned short* dh = &FtH[w * FT_S + hc];
    unsigned short* dl = &FtL[w * FT_S + hc];
    *(uint4*)(dh + 0) = *(uint4*)&hb[0];
    *(uint4*)(dh + 8) = *(uint4*)&hb[8];
    *(uint4*)(dl + 0) = *(uint4*)&lb[0];
    *(uint4*)(dl + 8) = *(uint4*)&lb[8];
  }
  __syncthreads();

  const int wm = (wave >> 1) * 32, wn = (wave & 1) * 32;
  const int fr = lane & 15, kq = (lane >> 4) * 8;

  f32x4 acc[2][2] = {};
#pragma unroll
  for (int kcc = 0; kcc < 2; ++kcc) {
    bf16x8 ah[2], al[2], bh[2], bl[2];
#pragma unroll
    for (int i = 0; i < 2; ++i) {
      ah[i] = *(const bf16x8*)&FtH[(wm + i * 16 + fr) * FT_S + kcc * 32 + kq];
      al[i] = *(const bf16x8*)&FtL[(wm + i * 16 + fr) * FT_S + kcc * 32 + kq];
      bh[i] = *(const bf16x8*)&FtH[(wn + i * 16 + fr) * FT_S + kcc * 32 + kq];
      bl[i] = *(const bf16x8*)&FtL[(wn + i * 16 + fr) * FT_S + kcc * 32 + kq];
    }
#pragma unroll
    for (int i = 0; i < 2; ++i)
#pragma unroll
      for (int j = 0; j < 2; ++j) {
        acc[i][j] = __builtin_amdgcn_mfma_f32_16x16x32_bf16(ah[i], bh[j], acc[i][j], 0, 0, 0);
        acc[i][j] = __builtin_amdgcn_mfma_f32_16x16x32_bf16(ah[i], bl[j], acc[i][j], 0, 0, 0);
        acc[i][j] = __builtin_amdgcn_mfma_f32_16x16x32_bf16(al[i], bh[j], acc[i][j], 0, 0, 0);
      }
  }

  const int rq = (lane >> 4) * 4;
#pragma unroll
  for (int i = 0; i < 2; ++i)
#pragma unroll
    for (int j = 0; j < 2; ++j) {
      const int n = wn + j * 16 + fr;
#pragma unroll
      for (int r = 0; r < 4; ++r) {
        const int m = wm + i * 16 + rq + r;
        Sc[m * 64 + n] = acc[i][j][r];
      }
    }
}

// ---------------------------------------------------------------------------
// K3 v7 = R3's v4 (full-row, 1024 thr — the measured-best shape; j-quarter
// regressed +44 us from fine-grained requests) with ONE rider: the middle
// (M,L) combine is parallelized across all 1024 threads via an 8-lane
// shuffle tree (was: 128 threads serial 64-iter x2 while 896 idle).
// ---------------------------------------------------------------------------
__global__ __launch_bounds__(1024, 4) void softmax_fuse_k(
    const float* __restrict__ S, const float* __restrict__ Fbuf,
    float* __restrict__ Out) {
  const int i = blockIdx.x;   // 0..63
  const int b = blockIdx.y;
  const int tid = threadIdx.x;
  const int jl = (tid & 15) * 4;
  const int g = tid >> 4;     // 0..63 (8 c's each)

  const size_t rowO = (size_t)(b * 2) * CHW + (size_t)i * WDIM;
  const size_t rowS = rowO + CHW;

  float4 xoc[8], xsc[8];
  float mo[4], lo[4], ms[4], ls[4];
#pragma unroll
  for (int k = 0; k < 4; ++k) { mo[k] = -1e30f; ms[k] = -1e30f; lo[k] = 0.f; ls[k] = 0.f; }

#pragma unroll
  for (int cc = 0; cc < 8; ++cc) {
    const int c = g * 8 + cc;
    const size_t off = (size_t)c * HW + jl;
    xoc[cc] = *(const float4*)&S[rowO + off];
    xsc[cc] = *(const float4*)&S[rowS + off];
    mo[0] = fmaxf(mo[0], xoc[cc].x); mo[1] = fmaxf(mo[1], xoc[cc].y);
    mo[2] = fmaxf(mo[2], xoc[cc].z); mo[3] = fmaxf(mo[3], xoc[cc].w);
    ms[0] = fmaxf(ms[0], xsc[cc].x); ms[1] = fmaxf(ms[1], xsc[cc].y);
    ms[2] = fmaxf(ms[2], xsc[cc].z); ms[3] = fmaxf(ms[3], xsc[cc].w);
  }
#pragma unroll
  for (int cc = 0; cc < 8; ++cc) {
    lo[0] += __expf(xoc[cc].x - mo[0]); lo[1] += __expf(xoc[cc].y - mo[1]);
    lo[2] += __expf(xoc[cc].z - mo[2]); lo[3] += __expf(xoc[cc].w - mo[3]);
    ls[0] += __expf(xsc[cc].x - ms[0]); ls[1] += __expf(xsc[cc].y - ms[1]);
    ls[2] += __expf(xsc[cc].z - ms[2]); ls[3] += __expf(xsc[cc].w - ms[3]);
  }

  __shared__ float sm[2][64][64];
  __shared__ float sl[2][64][64];
  __shared__ float Mf[2][64];
  __shared__ float Li[2][64];

  *(float4*)&sm[0][g][jl] = make_float4(mo[0], mo[1], mo[2], mo[3]);
  *(float4*)&sl[0][g][jl] = make_float4(lo[0], lo[1], lo[2], lo[3]);
  *(float4*)&sm[1][g][jl] = make_float4(ms[0], ms[1], ms[2], ms[3]);
  *(float4*)&sl[1][g][jl] = make_float4(ls[0], ls[1], ls[2], ls[3]);
  __syncthreads();

  {
    // (br, j, chunk): brx = tid>>9, jj = (tid>>3)&63, ch = tid&7 (low lane
    // bits -> shfl_xor 1/2/4 stays in the 8-lane group).
    const int brx = tid >> 9, jj = (tid >> 3) & 63, ch = tid & 7;
    float M = -1e30f;
#pragma unroll
    for (int t = 0; t < 8; ++t) M = fmaxf(M, sm[brx][ch * 8 + t][jj]);
#pragma unroll
    for (int d = 1; d < 8; d <<= 1) M = fmaxf(M, __shfl_xor(M, d));
    float L = 0.f;
#pragma unroll
    for (int t = 0; t < 8; ++t)
      L += sl[brx][ch * 8 + t][jj] * __expf(sm[brx][ch * 8 + t][jj] - M);
#pragma unroll
    for (int d = 1; d < 8; d <<= 1) L += __shfl_xor(L, d);
    if (ch == 0) {
      Mf[brx][jj] = M;
      Li[brx][jj] = 1.f / L;
    }
  }
  __syncthreads();

  float4 Mo4 = *(const float4*)&Mf[0][jl];
  float4 iLo4 = *(const float4*)&Li[0][jl];
  float4 Ms4 = *(const float4*)&Mf[1][jl];
  float4 iLs4 = *(const float4*)&Li[1][jl];
  float Mov[4] = {Mo4.x, Mo4.y, Mo4.z, Mo4.w};
  float iLov[4] = {iLo4.x, iLo4.y, iLo4.z, iLo4.w};
  float Msv[4] = {Ms4.x, Ms4.y, Ms4.z, Ms4.w};
  float iLsv[4] = {iLs4.x, iLs4.y, iLs4.z, iLs4.w};

#pragma unroll
  for (int cc = 0; cc < 8; ++cc) {
    const int c = g * 8 + cc;
    const size_t off = (size_t)c * HW + jl;
    float4 fo = *(const float4*)&Fbuf[rowO + off];
    float4 fs = *(const float4*)&Fbuf[rowS + off];
    float xov[4] = {xoc[cc].x, xoc[cc].y, xoc[cc].z, xoc[cc].w};
    float xsv[4] = {xsc[cc].x, xsc[cc].y, xsc[cc].z, xsc[cc].w};
    float fov[4] = {fo.x, fo.y, fo.z, fo.w};
    float fsv[4] = {fs.x, fs.y, fs.z, fs.w};
    float ov[4];
#pragma unroll
    for (int k = 0; k < 4; ++k) {
      const float ho = __expf(xov[k] - Mov[k]) * iLov[k];
      const float hs = __expf(xsv[k] - Msv[k]) * iLsv[k];
      float h2 = ho * hs;
      h2 *= h2;
      ov[k] = fov[k] * fsv[k] * h2;
    }
    *(float4*)&Out[(size_t)b * CHW + (size_t)c * HW + (size_t)i * WDIM + jl] =
        make_float4(ov[0], ov[1], ov[2], ov[3]);
  }
}

// ---------------------------------------------------------------------------
extern "C" void kernel_launch(void* const* d_in, const int* in_sizes, int n_in,
                              void* d_out, int out_size, void* d_ws, size_t ws_size,
                              hipStream_t stream) {
  const float* opt = (const float*)d_in[0];
  const float* sar = (const float*)d_in[1];
  const float* Wo  = (const float*)d_in[2];
  const float* Wsr = (const float*)d_in[3];
  float* out = (float*)d_out;

  // workspace: Whl | F | S
  unsigned short* Whl = (unsigned short*)d_ws;
  const size_t whlElems = 2u * 2u * 262144u;     // 2 MB
  const size_t perBl = 2 * CHW;                  // elems per batch (both br)
  const size_t perBlBytes = perBl * 8;           // F(4) + S(4)
  int bc = (int)((ws_size - whlElems * 2) / perBlBytes);
  if (bc < 1) bc = 1;
  if (bc > NBATCH) bc = NBATCH;
  const int passes = (NBATCH + bc - 1) / bc;
  const int nbp = (NBATCH + passes - 1) / passes;

  float* Fbuf = (float*)(Whl + whlElems);
  float* Sbuf = Fbuf + (size_t)bc * perBl;

  hipLaunchKernelGGL(wsplit_k, dim3(1024, 2), dim3(256), 0, stream, Wo, Wsr, Whl);

  for (int b0 = 0; b0 < NBATCH; b0 += nbp) {
    const int nb = (NBATCH - b0 < nbp) ? (NBATCH - b0) : nbp;

    hipLaunchKernelGGL(mfma_conv_k, dim3(32, 4, nb * 2), dim3(256), 0, stream,
                       Whl, opt, sar, Fbuf, b0);

    hipLaunchKernelGGL(gram_k, dim3(CCH, nb * 2), dim3(256), 0, stream,
                       Fbuf, Sbuf);

    hipLaunchKernelGGL(softmax_fuse_k, dim3(WDIM, nb), dim3(1024), 0, stream,
                       Sbuf, Fbuf, out + (size_t)b0 * CHW);
  }
}